// Round 3
// baseline (204.165 us; speedup 1.0000x reference)
//
#include <hip/hip_runtime.h>
#include <math.h>

#define DM   1024
#define DS   64
#define BATCH 8
#define SEQ  2048
#define CL   32          // chunk length
#define NC   64          // number of chunks (SEQ/CL)

typedef __bf16 bf16x8 __attribute__((ext_vector_type(8)));
typedef __bf16 bf16x4 __attribute__((ext_vector_type(4)));
typedef float  f32x4  __attribute__((ext_vector_type(4)));

// ---------------------------------------------------------------------------
// Kernel W: pre-convert W_delta|W_Bp|W_Cp into packed bf16, K-tiled:
// Wp[(kt*192 + n)*32 + kk], k = kt*32+kk.
// ---------------------------------------------------------------------------
__global__ __launch_bounds__(256) void wconv_kernel(
    const float* __restrict__ Wd, const float* __restrict__ Wb,
    const float* __restrict__ Wc, __bf16* __restrict__ Wp)
{
    int idx = blockIdx.x * 256 + threadIdx.x;   // n*1024 + k
    int k  = idx & 1023;
    int n  = idx >> 10;                          // 0..191
    const float* W = (n < 64) ? Wd : (n < 128 ? Wb : Wc);
    float v = W[(size_t)(n & 63) * DM + k];
    int kt = k >> 5, kk = k & 31;
    Wp[((size_t)kt * 192 + n) * 32 + kk] = (__bf16)v;
}

// ---------------------------------------------------------------------------
// Kernel A: MFMA projection, single bf16 plane (x and W both bf16; error
// ~1e-3 std in z, well under threshold). Double-buffered LDS, ONE barrier
// per k-tile: global loads for kt+1 issue before COMPUTE(kt) so VMEM hides
// under MFMA; STAGE writes go to the other buffer.
// Block: 32 M x 192 N, 256 thr (4 waves), grid 512 (2 blk/CU).
// Wave: M-half=(wv&1)*16, N-half=(wv>>1)*96. LDS rows stride 40 shorts
// (80 B = 16B-aligned; all b128 accesses service in the minimum 8 phases).
// ---------------------------------------------------------------------------
__global__ __launch_bounds__(256) void proj_mfma(
    const float* __restrict__ x, const __bf16* __restrict__ Wp,
    const float* __restrict__ bd, const float* __restrict__ bb,
    const float* __restrict__ bc,
    float* __restrict__ delta_g, float* __restrict__ u_g,
    float* __restrict__ ct_g)
{
    __shared__ __bf16 sA[2][32 * 40];            // 5.1 KB
    __shared__ __bf16 sB[2][192 * 40];           // 30.7 KB

    const int tid  = threadIdx.x;
    const int row0 = blockIdx.x * 32;

    const int sx_row = tid >> 3;                 // 0..31
    const int sx_sub = tid & 7;                  // 0..7
    const float* xg = x + (size_t)(row0 + sx_row) * DM + sx_sub * 4;
    const int wn0  = tid >> 2;                   // 0..63
    const int wsub = tid & 3;                    // 0..3

    const int lane = tid & 63, wv = tid >> 6;
    const int l15 = lane & 15, quad = lane >> 4;
    const int mrow  = (wv & 1) * 16;
    const int nbase = (wv >> 1) * 96;

    f32x4 acc[6];
    #pragma unroll
    for (int i = 0; i < 6; ++i) acc[i] = (f32x4){0.f, 0.f, 0.f, 0.f};

    float4 xr;
    uint4 w0, w1, w2;

    #define LOAD(kt) do {                                                     \
        xr = *(const float4*)(xg + (kt) * 32);                                \
        const __bf16* wp = Wp + ((size_t)(kt) * 192) * 32 + wsub * 8;         \
        w0 = *(const uint4*)(wp + (size_t)(wn0      ) * 32);                  \
        w1 = *(const uint4*)(wp + (size_t)(wn0 +  64) * 32);                  \
        w2 = *(const uint4*)(wp + (size_t)(wn0 + 128) * 32);                  \
    } while (0)

    #define STAGE(bi) do {                                                    \
        bf16x4 hv = {(__bf16)xr.x, (__bf16)xr.y, (__bf16)xr.z, (__bf16)xr.w}; \
        *(bf16x4*)&sA[bi][sx_row * 40 + sx_sub * 4] = hv;                     \
        *(uint4*)&sB[bi][(wn0      ) * 40 + wsub * 8] = w0;                   \
        *(uint4*)&sB[bi][(wn0 +  64) * 40 + wsub * 8] = w1;                   \
        *(uint4*)&sB[bi][(wn0 + 128) * 40 + wsub * 8] = w2;                   \
    } while (0)

    #define COMPUTE(bi) do {                                                  \
        bf16x8 ah = *(const bf16x8*)&sA[bi][(mrow + l15) * 40 + quad * 8];    \
        _Pragma("unroll")                                                     \
        for (int nt = 0; nt < 6; ++nt) {                                      \
            bf16x8 bf = *(const bf16x8*)                                      \
                &sB[bi][(nbase + nt * 16 + l15) * 40 + quad * 8];             \
            acc[nt] = __builtin_amdgcn_mfma_f32_16x16x32_bf16(                \
                ah, bf, acc[nt], 0, 0, 0);                                    \
        }                                                                     \
    } while (0)

    LOAD(0);
    STAGE(0);
    __syncthreads();

    int buf = 0;
    for (int kt = 0; kt < 32; ++kt) {
        if (kt < 31) LOAD(kt + 1);               // issue global early
        COMPUTE(buf);                            // MFMA hides VMEM latency
        if (kt < 31) STAGE(buf ^ 1);             // write other buffer
        __syncthreads();                         // one barrier per tile
        buf ^= 1;
    }

    // epilogue: bias + activations + stores
    #pragma unroll
    for (int nt = 0; nt < 6; ++nt) {
        int gn  = nbase + nt * 16 + l15;
        int mat = gn >> 6;
        int col = gn & 63;
        float bias = (mat == 0) ? bd[col] : (mat == 1 ? bb[col] : bc[col]);
        #pragma unroll
        for (int r = 0; r < 4; ++r) {
            int m = row0 + mrow + quad * 4 + r;
            float v = acc[nt][r] + bias;
            if (mat == 0) {
                float sp = (v > 20.f) ? v : log1pf(__expf(v));
                delta_g[(size_t)m * DS + col] = sp;
            } else if (mat == 1) {
                u_g[(size_t)m * DS + col] = v * x[(size_t)m * DM + col];
            } else {
                ct_g[(size_t)m * DS + col] = v;
            }
        }
    }
    #undef LOAD
    #undef STAGE
    #undef COMPUTE
}

// ---------------------------------------------------------------------------
// Kernel B (pass 1): per-chunk local recurrence from h=0.
// ---------------------------------------------------------------------------
__global__ __launch_bounds__(256) void pass1_kernel(
    const float* __restrict__ delta_g, const float* __restrict__ u_g,
    const float* __restrict__ A_log,
    float* __restrict__ E, float* __restrict__ Dsum)
{
    __shared__ float s_d[CL * 64];
    __shared__ float s_u[CL * 64];
    const int c = blockIdx.x, b = blockIdx.y, tid = threadIdx.x;
    const int t0 = c * CL;

    const float4* dg = (const float4*)(delta_g + ((size_t)b * SEQ + t0) * DS);
    const float4* ug = (const float4*)(u_g     + ((size_t)b * SEQ + t0) * DS);
    #pragma unroll
    for (int it = 0; it < (CL * 64 / 4) / 256; ++it) {
        int f = tid + it * 256;
        ((float4*)s_d)[f] = dg[f];
        ((float4*)s_u)[f] = ug[f];
    }

    const int i  = tid & 63;
    const int jg = tid >> 6;
    float alog[16];
    {
        const float4* ar = (const float4*)(A_log + i * 64 + jg * 16);
        #pragma unroll
        for (int q = 0; q < 4; ++q) {
            float4 v = ar[q];
            alog[4*q+0] = v.x; alog[4*q+1] = v.y;
            alog[4*q+2] = v.z; alog[4*q+3] = v.w;
        }
    }
    __syncthreads();

    float h[16];
    #pragma unroll
    for (int k = 0; k < 16; ++k) h[k] = 0.f;
    float dsum = 0.f;

    for (int t = 0; t < CL; ++t) {
        float d = s_d[t * 64 + i];
        dsum += d;
        const float* up = s_u + t * 64 + jg * 16;
        #pragma unroll
        for (int k = 0; k < 16; ++k)
            h[k] = __expf(alog[k] * d) * h[k] + up[k];
    }

    float* eo = E + (((size_t)c * BATCH + b) * 64 + i) * 64 + jg * 16;
    #pragma unroll
    for (int q = 0; q < 4; ++q)
        ((float4*)eo)[q] = make_float4(h[4*q], h[4*q+1], h[4*q+2], h[4*q+3]);
    if (jg == 0) Dsum[((size_t)c * BATCH + b) * 64 + i] = dsum;
}

// ---------------------------------------------------------------------------
// Kernel C (pass 2): sequential chunk scan, parallel over B*64*64 elements.
// Decay exp() is OFF the carry chain; E/Dsum prefetched 4 iterations ahead
// so the ~200-cyc L2 latency hides behind 4 x (fma-chain) iterations.
// ---------------------------------------------------------------------------
__global__ __launch_bounds__(256) void pass2_kernel(
    const float* __restrict__ A_log, const float* __restrict__ E,
    const float* __restrict__ Dsum, float* __restrict__ Sin)
{
    const int g = blockIdx.x * 256 + threadIdx.x;     // 0..32767
    const int b = g >> 12;
    const int e = g & 4095;
    const int i = e >> 6;
    const float al = A_log[e];

    float Eb[4], db[4];
    #pragma unroll
    for (int p = 0; p < 4; ++p) {
        size_t nb = (size_t)p * BATCH + b;
        Eb[p] = E[nb * 4096 + e];
        db[p] = __expf(al * Dsum[nb * 64 + i]);
    }

    float carry = 0.f;
    #pragma unroll 4
    for (int c = 0; c < NC; ++c) {
        const int s = c & 3;
        float Ec = Eb[s], dc = db[s];
        if (c + 4 < NC) {
            size_t nb = (size_t)(c + 4) * BATCH + b;
            Eb[s] = E[nb * 4096 + e];
            db[s] = __expf(al * Dsum[nb * 64 + i]);
        }
        Sin[((size_t)c * BATCH + b) * 4096 + e] = carry;
        carry = dc * carry + Ec;                      // the only serial dep
    }
}

// ---------------------------------------------------------------------------
// Kernel D (pass 3): replay chunk from true incoming state, emit
//   y[b,t,i] = sum_j Ct[b,t,j] * h[b,i,j]
// Thread -> (i = tid>>2, jg = tid&3): the 4 j-partials for an i sit in
// ADJACENT LANES -> 2x shfl_xor reduction, NO in-loop barriers (was 32).
// LDS reads: s_d broadcast 4-lane same-addr; s_u/s_c 2-way max (free).
// ---------------------------------------------------------------------------
__global__ __launch_bounds__(256) void pass3_kernel(
    const float* __restrict__ delta_g, const float* __restrict__ u_g,
    const float* __restrict__ ct_g, const float* __restrict__ A_log,
    const float* __restrict__ Sin, float* __restrict__ out)
{
    __shared__ float s_d[CL * 64];
    __shared__ float s_u[CL * 64];
    __shared__ float s_c[CL * 64];

    const int c = blockIdx.x, b = blockIdx.y, tid = threadIdx.x;
    const int t0 = c * CL;

    const float4* dg = (const float4*)(delta_g + ((size_t)b * SEQ + t0) * DS);
    const float4* ug = (const float4*)(u_g     + ((size_t)b * SEQ + t0) * DS);
    const float4* cg = (const float4*)(ct_g    + ((size_t)b * SEQ + t0) * DS);
    #pragma unroll
    for (int it = 0; it < (CL * 64 / 4) / 256; ++it) {
        int f = tid + it * 256;
        ((float4*)s_d)[f] = dg[f];
        ((float4*)s_u)[f] = ug[f];
        ((float4*)s_c)[f] = cg[f];
    }

    const int i  = tid >> 2;                          // 0..63
    const int jg = tid & 3;                           // 0..3

    float alog[16];
    {
        const float4* ar = (const float4*)(A_log + i * 64 + jg * 16);
        #pragma unroll
        for (int q = 0; q < 4; ++q) {
            float4 v = ar[q];
            alog[4*q+0] = v.x; alog[4*q+1] = v.y;
            alog[4*q+2] = v.z; alog[4*q+3] = v.w;
        }
    }

    float h[16];
    {
        const float4* hin = (const float4*)(
            Sin + (((size_t)c * BATCH + b) * 64 + i) * 64 + jg * 16);
        #pragma unroll
        for (int q = 0; q < 4; ++q) {
            float4 v = hin[q];
            h[4*q+0] = v.x; h[4*q+1] = v.y; h[4*q+2] = v.z; h[4*q+3] = v.w;
        }
    }
    __syncthreads();

    for (int t = 0; t < CL; ++t) {
        float d = s_d[t * 64 + i];
        const float* up = s_u + t * 64 + jg * 16;
        const float* cp = s_c + t * 64 + jg * 16;
        float part = 0.f;
        #pragma unroll
        for (int k = 0; k < 16; ++k) {
            h[k] = __expf(alog[k] * d) * h[k] + up[k];
            part += cp[k] * h[k];
        }
        part += __shfl_xor(part, 1);
        part += __shfl_xor(part, 2);
        if (jg == 0)
            out[((size_t)b * SEQ + t0 + t) * DS + i] = part;
    }
}

// ---------------------------------------------------------------------------
// Inputs: 0:x 1..6:(cog/beh/env dead) 7:W_delta 8:b_delta 9:W_Bp 10:b_Bp
//         11:W_Cp 12:b_Cp 13:A_log
// ---------------------------------------------------------------------------
extern "C" void kernel_launch(void* const* d_in, const int* in_sizes, int n_in,
                              void* d_out, int out_size, void* d_ws, size_t ws_size,
                              hipStream_t stream)
{
    const float* x     = (const float*)d_in[0];
    const float* Wd    = (const float*)d_in[7];
    const float* bd    = (const float*)d_in[8];
    const float* Wb    = (const float*)d_in[9];
    const float* bb    = (const float*)d_in[10];
    const float* Wc    = (const float*)d_in[11];
    const float* bc    = (const float*)d_in[12];
    const float* A_log = (const float*)d_in[13];
    float* out = (float*)d_out;

    float* ws = (float*)d_ws;
    float* delta_g = ws;                       // 1,048,576 floats
    float* u_g     = ws + 1 * 1048576;         // 1,048,576
    float* ct_g    = ws + 2 * 1048576;         // 1,048,576
    float* E       = ws + 3 * 1048576;         // 2,097,152
    float* Sin     = ws + 5 * 1048576;         // 2,097,152
    float* Dsum    = ws + 7 * 1048576;         // 32,768
    __bf16* Wp     = (__bf16*)E;               // aliases E (dead by pass1)

    wconv_kernel<<<768, 256, 0, stream>>>(Wd, Wb, Wc, Wp);
    proj_mfma<<<512, 256, 0, stream>>>(
        x, Wp, bd, bb, bc, delta_g, u_g, ct_g);
    pass1_kernel<<<dim3(NC, BATCH), 256, 0, stream>>>(
        delta_g, u_g, A_log, E, Dsum);
    pass2_kernel<<<(BATCH * 4096) / 256, 256, 0, stream>>>(
        A_log, E, Dsum, Sin);
    pass3_kernel<<<dim3(NC, BATCH), 256, 0, stream>>>(
        delta_g, u_g, ct_g, A_log, Sin, out);
}